// Round 1
// baseline (2637.161 us; speedup 1.0000x reference)
//
#include <hip/hip_runtime.h>

// ---------------------------------------------------------------------------
// Bidirectional 2-layer GRU (B=256, T=256, H=256, IN0=4) + head.
//
// Plan:
//  prep_wf   : pack Whh0[d0], Whh0[d1], Whh1[d0] (fp32) -> bf16 MFMA-fragment
//              order [mat][nt48][kk8][lane64][8] so recurrence streams weights
//              with coalesced dwordx4 loads from L2.
//  prep_w1b  : Wih1[d0] fp32 -> bf16 row-major [768][512] for the xp1 GEMM.
//  gru_rec<0>: 32 WGs (16 fwd + 16 bwd), each owns 16 batch rows, loops 256
//              steps. h state fp32 in regs; bf16 copy in XOR-swizzled LDS
//              (double buffered, 1 barrier/step). Whh streamed from L2.
//              Writes h0 concat bf16 [B*T, 512].
//  xp1_gemm  : [65536,512]@[512,768] bf16 MFMA GEMM + bih1 -> xp1 bf16.
//  bwd255    : layer-1 bwd dir needs only t=T-1 output = ONE step from h=0.
//  gru_rec<1>: layer-1 fwd recurrence (16 WGs), reads xp1, keeps final h.
//  head      : (h_fwd_last + h_bwd255) @ W_out.T + b_out -> softmax(3).
//
// Workspace layout (bytes), total ~171.5 MB:
//   0          wfall  : 3 * 768*256 bf16 = 2,359,296
//   2359296    w1b    : 768*512 bf16     =   786,432
//   3145728    h0c    : 65536*512 bf16   = 67,108,864
//   70254592   xp1    : 65536*768 bf16   = 100,663,296
//   170917888  hb255  : 256*256 f32      =   262,144
//   171180032  hfl    : 256*256 f32      =   262,144
// ---------------------------------------------------------------------------

typedef __attribute__((ext_vector_type(8))) short short8;
typedef __attribute__((ext_vector_type(4))) float f32x4;

__device__ __forceinline__ short f2bf(float f) {
  union { float f; unsigned u; } v; v.f = f;
  unsigned r = v.u + 0x7fffu + ((v.u >> 16) & 1u);   // round-to-nearest-even
  return (short)(r >> 16);
}
__device__ __forceinline__ float bf2f(unsigned short b) {
  union { unsigned u; float f; } v; v.u = ((unsigned)b) << 16; return v.f;
}
__device__ __forceinline__ float sigf(float x) {
  return __builtin_amdgcn_rcpf(1.f + __expf(-x));
}
__device__ __forceinline__ float tanhf_(float x) {
  return 1.f - 2.f * __builtin_amdgcn_rcpf(1.f + __expf(2.f * x));
}

// --------------------------- prep kernels ----------------------------------

// out[mat][nt][kk][lane][s] = W[mat](nt*16 + (lane&15), kk*32 + (lane>>4)*8 + s)
// mats: 0 = Whh0 dir0, 1 = Whh0 dir1, 2 = Whh1 dir0. Each W is [768][256] f32.
__global__ __launch_bounds__(256) void prep_wf(const float* __restrict__ whh0,
                                               const float* __restrict__ whh1,
                                               short* __restrict__ out) {
  int tid = blockIdx.x * 256 + threadIdx.x;          // 0 .. 73727
  int l  = tid & 63;
  int kk = (tid >> 6) & 7;
  int nt = (tid >> 9) % 48;
  int m  = tid / (48 * 8 * 64);
  const float* src = (m < 2) ? (whh0 + (size_t)m * 768 * 256) : whh1;
  int row = nt * 16 + (l & 15);
  int k0  = kk * 32 + ((l >> 4) << 3);
  const float* p = src + (size_t)row * 256 + k0;
  short8 o;
  #pragma unroll
  for (int s = 0; s < 8; ++s) o[s] = f2bf(p[s]);
  ((short8*)out)[tid] = o;
}

// Wih1 dir0 fp32 [768][512] -> bf16 row-major.
__global__ __launch_bounds__(256) void prep_w1b(const float* __restrict__ wih1,
                                                short* __restrict__ out) {
  int i = blockIdx.x * 256 + threadIdx.x;            // each converts 8 elems
  const float* p = wih1 + (size_t)i * 8;
  short8 o;
  #pragma unroll
  for (int s = 0; s < 8; ++s) o[s] = f2bf(p[s]);
  ((short8*)out)[i] = o;
}

// --------------------------- recurrence kernel -----------------------------
// 8 waves, 16 batch rows per WG. Wave w owns hidden cols [32w, 32w+32):
// N-tiles {2w,2w+1} (r), {16+2w,17+2w} (z), {32+2w,33+2w} (n).
// LDS h: [16][256] bf16, 16B-granule XOR swizzle: granule' = granule ^ (row&7).

template <int LAYER>
__global__ __launch_bounds__(512) void gru_rec(
    const float* __restrict__ x,        // L0: [256][256][4]
    const float* __restrict__ wih0,     // L0: [2][768][4]
    const float* __restrict__ bih0,     // L0: [2][768]
    const float* __restrict__ bhh,      // [2][768] (this layer's bhh)
    const short* __restrict__ wf,       // frag-packed Whh for this layer
    const unsigned short* __restrict__ xp1, // L1: bf16 [65536][768]
    short* __restrict__ h0c,            // L0 out: bf16 [65536][512]
    float* __restrict__ hlast) {        // L1 out: f32 [256][256]
  const int wg  = blockIdx.x;
  const int dir = (LAYER == 0) ? (wg >> 4) : 0;
  const int bt  = (LAYER == 0) ? (wg & 15) : wg;
  const int b0  = bt << 4;
  const int tid = threadIdx.x;
  const int w   = tid >> 6;
  const int l   = tid & 63;
  const int l15 = l & 15, lhi = l >> 4;

  __shared__ __align__(16) short hbuf[2][4096];
  for (int i = tid; i < 8192; i += 512) ((short*)hbuf)[i] = 0;

  int nt[6];
  nt[0] = 2 * w;      nt[1] = 2 * w + 1;
  nt[2] = 16 + 2 * w; nt[3] = 17 + 2 * w;
  nt[4] = 32 + 2 * w; nt[5] = 33 + 2 * w;
  const short8* wfv = (const short8*)wf + (size_t)dir * (48 * 8 * 64);

  float bhhv[6], bihv[6];
  float4 wr4[6];
  #pragma unroll
  for (int g = 0; g < 3; ++g)
    #pragma unroll
    for (int sub = 0; sub < 2; ++sub) {
      int gcol = g * 256 + w * 32 + sub * 16 + l15;
      bhhv[g * 2 + sub] = bhh[dir * 768 + gcol];
      if (LAYER == 0) {
        wr4[g * 2 + sub]  = ((const float4*)wih0)[dir * 768 + gcol];
        bihv[g * 2 + sub] = bih0[dir * 768 + gcol];
      }
    }

  float hreg[2][4] = {};
  int cur = 0;
  __syncthreads();

  for (int t = 0; t < 256; ++t) {
    const int tact = (LAYER == 0 && dir == 1) ? (255 - t) : t;

    // --- issue input loads early (consumed in elementwise phase) ---
    float4 xv[4];
    unsigned short xpu[6][4];
    if (LAYER == 0) {
      #pragma unroll
      for (int i = 0; i < 4; ++i)
        xv[i] = ((const float4*)x)[(size_t)(b0 + lhi * 4 + i) * 256 + tact];
    } else {
      #pragma unroll
      for (int q = 0; q < 6; ++q) {
        int gc = (q >> 1) * 256 + w * 32 + (q & 1) * 16 + l15;
        #pragma unroll
        for (int i = 0; i < 4; ++i)
          xpu[q][i] = xp1[(size_t)((b0 + lhi * 4 + i) * 256 + tact) * 768 + gc];
      }
    }

    // --- A fragments from swizzled LDS ---
    short8 af[8];
    #pragma unroll
    for (int kk = 0; kk < 8; ++kk) {
      int g = kk * 4 + lhi;
      af[kk] = *(const short8*)&hbuf[cur][l15 * 256 + ((g ^ (l15 & 7)) << 3)];
    }

    // --- MFMA with double-buffered streamed weights ---
    f32x4 acc[6] = {};
    short8 wb0[6], wb1[6];
    #pragma unroll
    for (int q = 0; q < 6; ++q) wb0[q] = wfv[(nt[q] * 8 + 0) * 64 + l];
    #pragma unroll
    for (int kk = 0; kk < 8; ++kk) {
      short8* cb = (kk & 1) ? wb1 : wb0;
      short8* nb = (kk & 1) ? wb0 : wb1;
      if (kk < 7) {
        #pragma unroll
        for (int q = 0; q < 6; ++q) nb[q] = wfv[(nt[q] * 8 + (kk + 1)) * 64 + l];
      }
      #pragma unroll
      for (int q = 0; q < 6; ++q)
        acc[q] = __builtin_amdgcn_mfma_f32_16x16x32_bf16(af[kk], cb[q], acc[q], 0, 0, 0);
    }

    // --- elementwise GRU cell ---
    const int nxt = cur ^ 1;
    #pragma unroll
    for (int sub = 0; sub < 2; ++sub) {
      const int col = w * 32 + sub * 16 + l15;
      #pragma unroll
      for (int i = 0; i < 4; ++i) {
        float xr, xz, xn;
        if (LAYER == 0) {
          float4 v = xv[i];
          float4 a0 = wr4[sub], a1 = wr4[2 + sub], a2 = wr4[4 + sub];
          xr = v.x * a0.x + v.y * a0.y + v.z * a0.z + v.w * a0.w + bihv[sub];
          xz = v.x * a1.x + v.y * a1.y + v.z * a1.z + v.w * a1.w + bihv[2 + sub];
          xn = v.x * a2.x + v.y * a2.y + v.z * a2.z + v.w * a2.w + bihv[4 + sub];
        } else {
          xr = bf2f(xpu[sub][i]);
          xz = bf2f(xpu[2 + sub][i]);
          xn = bf2f(xpu[4 + sub][i]);
        }
        float r  = sigf(xr + acc[sub][i] + bhhv[sub]);
        float z  = sigf(xz + acc[2 + sub][i] + bhhv[2 + sub]);
        float hn = acc[4 + sub][i] + bhhv[4 + sub];
        float n  = tanhf_(xn + r * hn);
        float h  = hreg[sub][i];
        float hnw = n + z * (h - n);
        hreg[sub][i] = hnw;
        short hb16 = f2bf(hnw);
        int row = lhi * 4 + i;
        hbuf[nxt][row * 256 + (((col >> 3) ^ (row & 7)) << 3) + (col & 7)] = hb16;
        if (LAYER == 0)
          h0c[(size_t)((b0 + row) * 256 + tact) * 512 + dir * 256 + col] = hb16;
      }
    }
    __syncthreads();
    cur ^= 1;
  }

  if (LAYER == 1) {
    #pragma unroll
    for (int sub = 0; sub < 2; ++sub) {
      const int col = w * 32 + sub * 16 + l15;
      #pragma unroll
      for (int i = 0; i < 4; ++i)
        hlast[(size_t)(b0 + lhi * 4 + i) * 256 + col] = hreg[sub][i];
    }
  }
}

// --------------------------- xp1 GEMM --------------------------------------
// xp1[rt, g] = sum_k h0c[rt, k] * Wih1[0][g, k] + bih1[0][g], bf16 out.
// 128x128 tile, BK=64, 4 waves (wave tile 64x64), swizzled LDS.
__global__ __launch_bounds__(256, 2) void xp1_gemm(
    const short* __restrict__ h0c, const short* __restrict__ w1b,
    const float* __restrict__ bih1, unsigned short* __restrict__ xp1) {
  const int mb = blockIdx.x, nb = blockIdx.y;
  const int tid = threadIdx.x;
  const int w = tid >> 6, l = tid & 63, l15 = l & 15, lhi = l >> 4;
  const int wm = w >> 1, wn = w & 1;
  __shared__ __align__(16) short As[128 * 64];
  __shared__ __align__(16) short Bs[128 * 64];
  f32x4 acc[4][4] = {};

  for (int ks = 0; ks < 8; ++ks) {
    short8 sa[4], sb[4];
    #pragma unroll
    for (int c = 0; c < 4; ++c) {
      int li = w * 256 + c * 64 + l;
      int row = li >> 3, cg = li & 7;
      sa[c] = *(const short8*)(h0c + (size_t)(mb * 128 + row) * 512 + ks * 64 + cg * 8);
      sb[c] = *(const short8*)(w1b + (size_t)(nb * 128 + row) * 512 + ks * 64 + cg * 8);
    }
    __syncthreads();                       // previous compute done with LDS
    #pragma unroll
    for (int c = 0; c < 4; ++c) {
      int li = w * 256 + c * 64 + l;
      int row = li >> 3, cg = li & 7;
      int sl = ((cg ^ (row & 7)) << 3);
      *(short8*)&As[row * 64 + sl] = sa[c];
      *(short8*)&Bs[row * 64 + sl] = sb[c];
    }
    __syncthreads();
    short8 af[4][2], bf[4][2];
    #pragma unroll
    for (int mt = 0; mt < 4; ++mt)
      #pragma unroll
      for (int kk = 0; kk < 2; ++kk) {
        int row = wm * 64 + mt * 16 + l15;
        int g = kk * 4 + lhi;
        af[mt][kk] = *(const short8*)&As[row * 64 + ((g ^ (row & 7)) << 3)];
      }
    #pragma unroll
    for (int nt2 = 0; nt2 < 4; ++nt2)
      #pragma unroll
      for (int kk = 0; kk < 2; ++kk) {
        int row = wn * 64 + nt2 * 16 + l15;
        int g = kk * 4 + lhi;
        bf[nt2][kk] = *(const short8*)&Bs[row * 64 + ((g ^ (row & 7)) << 3)];
      }
    #pragma unroll
    for (int kk = 0; kk < 2; ++kk)
      #pragma unroll
      for (int mt = 0; mt < 4; ++mt)
        #pragma unroll
        for (int nt2 = 0; nt2 < 4; ++nt2)
          acc[mt][nt2] = __builtin_amdgcn_mfma_f32_16x16x32_bf16(
              af[mt][kk], bf[nt2][kk], acc[mt][nt2], 0, 0, 0);
  }

  float bi[4];
  #pragma unroll
  for (int nt2 = 0; nt2 < 4; ++nt2)
    bi[nt2] = bih1[nb * 128 + wn * 64 + nt2 * 16 + l15];
  #pragma unroll
  for (int mt = 0; mt < 4; ++mt)
    #pragma unroll
    for (int nt2 = 0; nt2 < 4; ++nt2)
      #pragma unroll
      for (int i = 0; i < 4; ++i) {
        int rt = mb * 128 + wm * 64 + mt * 16 + lhi * 4 + i;
        int cc = nb * 128 + wn * 64 + nt2 * 16 + l15;
        xp1[(size_t)rt * 768 + cc] = (unsigned short)f2bf(acc[mt][nt2][i] + bi[nt2]);
      }
}

// --------------------------- layer-1 bwd, single step ----------------------
// h2_bwd[:, T-1] = one GRU step from h=0 using Wih1[1]/bih1[1]/bhh1[1].
__global__ __launch_bounds__(256) void bwd255(
    const short* __restrict__ h0c, const float* __restrict__ wih1,
    const float* __restrict__ bih1, const float* __restrict__ bhh1,
    float* __restrict__ hb) {
  const int b = blockIdx.x, j = threadIdx.x;
  __shared__ __align__(16) float hrow[512];
  const unsigned short* hr = (const unsigned short*)(h0c + (size_t)(b * 256 + 255) * 512);
  for (int k = j; k < 512; k += 256) hrow[k] = bf2f(hr[k]);
  __syncthreads();
  const float4* hr4 = (const float4*)hrow;
  float g[3];
  #pragma unroll
  for (int gi = 0; gi < 3; ++gi) {
    const float4* wr = (const float4*)(wih1 + (size_t)768 * 512 + (size_t)(gi * 256 + j) * 512);
    float s = 0.f;
    #pragma unroll 4
    for (int k = 0; k < 128; ++k) {
      float4 a = hr4[k], bq = wr[k];
      s += a.x * bq.x + a.y * bq.y + a.z * bq.z + a.w * bq.w;
    }
    g[gi] = s + bih1[768 + gi * 256 + j];
  }
  float r = sigf(g[0] + bhh1[768 + j]);
  float z = sigf(g[1] + bhh1[768 + 256 + j]);
  float n = tanhf_(g[2] + r * bhh1[768 + 512 + j]);
  hb[b * 256 + j] = (1.f - z) * n;
}

// --------------------------- head ------------------------------------------
__global__ __launch_bounds__(64) void head(
    const float* __restrict__ hf, const float* __restrict__ hb,
    const float* __restrict__ wout, const float* __restrict__ bout,
    float* __restrict__ out) {
  const int b = blockIdx.x, l = threadIdx.x;
  float s0 = 0.f, s1 = 0.f, s2 = 0.f;
  for (int k = l; k < 256; k += 64) {
    float v = hf[b * 256 + k] + hb[b * 256 + k];
    s0 += v * wout[k];
    s1 += v * wout[256 + k];
    s2 += v * wout[512 + k];
  }
  #pragma unroll
  for (int off = 32; off > 0; off >>= 1) {
    s0 += __shfl_down(s0, off);
    s1 += __shfl_down(s1, off);
    s2 += __shfl_down(s2, off);
  }
  if (l == 0) {
    s0 += bout[0]; s1 += bout[1]; s2 += bout[2];
    float m = fmaxf(s0, fmaxf(s1, s2));
    float e0 = __expf(s0 - m), e1 = __expf(s1 - m), e2 = __expf(s2 - m);
    float inv = 1.f / (e0 + e1 + e2);
    out[b * 3 + 0] = e0 * inv;
    out[b * 3 + 1] = e1 * inv;
    out[b * 3 + 2] = e2 * inv;
  }
}

// --------------------------- launch ----------------------------------------
extern "C" void kernel_launch(void* const* d_in, const int* in_sizes, int n_in,
                              void* d_out, int out_size, void* d_ws, size_t ws_size,
                              hipStream_t stream) {
  const float* x    = (const float*)d_in[0];
  const float* wih0 = (const float*)d_in[1];
  const float* whh0 = (const float*)d_in[2];
  const float* bih0 = (const float*)d_in[3];
  const float* bhh0 = (const float*)d_in[4];
  const float* wih1 = (const float*)d_in[5];
  const float* whh1 = (const float*)d_in[6];
  const float* bih1 = (const float*)d_in[7];
  const float* bhh1 = (const float*)d_in[8];
  const float* wout = (const float*)d_in[9];
  const float* bout = (const float*)d_in[10];
  float* out = (float*)d_out;

  char* ws = (char*)d_ws;
  short* wfall          = (short*)(ws);                 // 3 packed Whh mats
  short* w1b            = (short*)(ws + 2359296);
  short* h0c            = (short*)(ws + 3145728);
  unsigned short* xp1   = (unsigned short*)(ws + 70254592);
  float* hb255          = (float*)(ws + 170917888);
  float* hfl            = (float*)(ws + 171180032);

  prep_wf<<<288, 256, 0, stream>>>(whh0, whh1, wfall);
  prep_w1b<<<192, 256, 0, stream>>>(wih1, w1b);
  gru_rec<0><<<32, 512, 0, stream>>>(x, wih0, bih0, bhh0, wfall, nullptr, h0c, nullptr);
  xp1_gemm<<<dim3(512, 6), 256, 0, stream>>>(h0c, w1b, bih1, xp1);
  bwd255<<<256, 256, 0, stream>>>(h0c, wih1, bih1, bhh1, hb255);
  gru_rec<1><<<16, 512, 0, stream>>>(nullptr, nullptr, nullptr, bhh1,
                                     wfall + 2 * 393216 / 2, xp1, nullptr, hfl);
  head<<<256, 64, 0, stream>>>(hfl, hb255, wout, bout, out);
}